// Round 1
// baseline (441.379 us; speedup 1.0000x reference)
//
#include <hip/hip_runtime.h>
#include <stdint.h>

#define T_STEPS 2048

struct F3 { float x, y, z; };

__device__ __forceinline__ F3 fma3(float a, F3 b, F3 c) {
    return { fmaf(a, b.x, c.x), fmaf(a, b.y, c.y), fmaf(a, b.z, c.z) };
}

// accel(p) = -gm * p / (|p|^2 + b^2)^1.5
__device__ __forceinline__ F3 accelF(F3 p, float gm, float b2) {
    float r2 = fmaf(p.z, p.z, fmaf(p.y, p.y, fmaf(p.x, p.x, b2)));
    float iv = rsqrtf(r2);
    float c  = -gm * (iv * iv * iv);
    return { c * p.x, c * p.y, c * p.z };
}

__device__ __forceinline__ uint32_t rotl32(uint32_t v, int r) {
    return (v << r) | (v >> (32 - r));
}

// JAX Threefry-2x32, 20 rounds.
__device__ __forceinline__ void tf2x32(uint32_t k0, uint32_t k1, uint32_t c0, uint32_t c1,
                                       uint32_t &o0, uint32_t &o1) {
    uint32_t ks2 = k0 ^ k1 ^ 0x1BD11BDAu;
    uint32_t x0 = c0 + k0, x1 = c1 + k1;
#define TF_R(r) { x0 += x1; x1 = rotl32(x1, r); x1 ^= x0; }
    TF_R(13) TF_R(15) TF_R(26) TF_R(6)   x0 += k1;  x1 += ks2 + 1u;
    TF_R(17) TF_R(29) TF_R(16) TF_R(24)  x0 += ks2; x1 += k0 + 2u;
    TF_R(13) TF_R(15) TF_R(26) TF_R(6)   x0 += k0;  x1 += k1 + 3u;
    TF_R(17) TF_R(29) TF_R(16) TF_R(24)  x0 += k1;  x1 += ks2 + 4u;
    TF_R(13) TF_R(15) TF_R(26) TF_R(6)   x0 += ks2; x1 += k0 + 5u;
#undef TF_R
    o0 = x0; o1 = x1;
}

// XLA ErfInv32 (Giles), w = -log1p(-x*x)
__device__ __forceinline__ float erfinv32(float x) {
    float w = -log1pf(-x * x);
    float p;
    if (w < 5.0f) {
        w -= 2.5f;
        p =              2.81022636e-08f;
        p = fmaf(p, w,   3.43273939e-07f);
        p = fmaf(p, w,  -3.5233877e-06f);
        p = fmaf(p, w,  -4.39150654e-06f);
        p = fmaf(p, w,   0.00021858087f);
        p = fmaf(p, w,  -0.00125372503f);
        p = fmaf(p, w,  -0.00417768164f);
        p = fmaf(p, w,   0.246640727f);
        p = fmaf(p, w,   1.50140941f);
    } else {
        w = sqrtf(w) - 3.0f;
        p =             -0.000200214257f;
        p = fmaf(p, w,   0.000100950558f);
        p = fmaf(p, w,   0.00134934322f);
        p = fmaf(p, w,  -0.00367342844f);
        p = fmaf(p, w,   0.00573950773f);
        p = fmaf(p, w,  -0.0076224613f);
        p = fmaf(p, w,   0.00943887047f);
        p = fmaf(p, w,   1.00167406f);
        p = fmaf(p, w,   2.83297682f);
    }
    return p * x;
}

// jax.random.normal (threefry, partitionable path): bits = x0^x1 of E(key,(0,idx))
__device__ __forceinline__ float jax_normal(uint32_t ka, uint32_t kb, uint32_t idx) {
    uint32_t o0, o1;
    tf2x32(ka, kb, 0u, idx, o0, o1);
    uint32_t bits = o0 ^ o1;
    float f = __uint_as_float((bits >> 9) | 0x3F800000u) - 1.0f;  // [0,1)
    const float LO = -0.99999994f;                                 // nextafter(-1,0)
    float u = fmaxf(LO, fmaf(f, 2.0f, LO));                        // hi-lo rounds to 2.0f
    return 1.41421356f * erfinv32(u);
}

// ---------------- progenitor: one serial chain, writes prog_ws rows ----------------
__global__ void prog_kernel(const float* __restrict__ ts,
                            const float* __restrict__ w0,
                            const float* __restrict__ gm_p,
                            const float* __restrict__ b_p,
                            float* __restrict__ prog) {
    if (threadIdx.x != 0 || blockIdx.x != 0) return;
    const float gm = gm_p[0];
    const float bb = b_p[0];
    const float b2 = bb * bb;

    F3 x = { w0[0], w0[1], w0[2] };
    F3 v = { w0[3], w0[4], w0[5] };
    prog[0] = x.x; prog[1] = x.y; prog[2] = x.z;
    prog[3] = v.x; prog[4] = v.y; prog[5] = v.z;

    // first step (j=0): v1 = v + h*a(x); x += dt*v1; v2 = v1 + h*a(x')
    F3 a = accelF(x, gm, b2);
    float ts_cur = ts[0];
    float ts_nxt = ts[1];
    float dt = ts_nxt - ts_cur, h = 0.5f * dt;
    ts_cur = ts_nxt;
    F3 u = fma3(h, a, v);
    x = fma3(dt, u, x);
    a = accelF(x, gm, b2);
    u = fma3(h, a, u);
    prog[6] = x.x; prog[7] = x.y; prog[8] = x.z;
    prog[9] = u.x; prog[10] = u.y; prog[11] = u.z;

    for (int j = 1; j < T_STEPS - 1; ++j) {
        ts_nxt = ts[j + 1];
        dt = ts_nxt - ts_cur; ts_cur = ts_nxt;
        h = 0.5f * dt;
        u = fma3(h, a, u);          // v1_j = v2_{j-1} + h*a(x_j)  (same accel value)
        x = fma3(dt, u, x);         // drift
        a = accelF(x, gm, b2);
        u = fma3(h, a, u);          // v2_j
        float* row = prog + 6 * (j + 1);
        row[0] = x.x; row[1] = x.y; row[2] = x.z;
        row[3] = u.x; row[4] = u.y; row[5] = u.z;
    }
}

// ---------------- stream particles: thread t handles lead+trail (2-way ILP) ----------------
__global__ void stream_kernel(const float* __restrict__ ts,
                              const float* __restrict__ prog,
                              const float* __restrict__ mass_p,
                              const float* __restrict__ gm_p,
                              const float* __restrict__ b_p,
                              const int*   __restrict__ seed_p,
                              float* __restrict__ w_lead,
                              float* __restrict__ w_trail) {
    const int t = blockIdx.x * blockDim.x + threadIdx.x;
    if (t >= T_STEPS) return;
    const float gm = gm_p[0];
    const float bb = b_p[0];
    const float b2 = bb * bb;
    const float pm = mass_p[0];
    const uint32_t seed = (uint32_t)seed_p[0];

    // split(key(seed), 4), foldlike: k_i = E((0,seed), (0,i))
    uint32_t k1a, k1b, k2a, k2b, k3a, k3b, k4a, k4b;
    tf2x32(0u, seed, 0u, 0u, k1a, k1b);
    tf2x32(0u, seed, 0u, 1u, k2a, k2b);
    tf2x32(0u, seed, 0u, 2u, k3a, k3b);
    tf2x32(0u, seed, 0u, 3u, k4a, k4b);

    const float* pr = prog + 6 * t;
    F3 px = { pr[0], pr[1], pr[2] };
    F3 pv = { pr[3], pr[4], pr[5] };

    float r   = sqrtf(fmaf(px.z, px.z, fmaf(px.y, px.y, px.x * px.x)));
    float cb  = powf(pm / (3.0f * gm), 1.0f / 3.0f);
    float rt  = r * cb;
    float sig = sqrtf(pm / (rt + 1e-8f));
    F3 rhat = { px.x / r, px.y / r, px.z / r };

    uint32_t base = 3u * (uint32_t)t;
    F3 n1 = { jax_normal(k1a, k1b, base + 0u), jax_normal(k1a, k1b, base + 1u), jax_normal(k1a, k1b, base + 2u) };
    F3 n2 = { jax_normal(k2a, k2b, base + 0u), jax_normal(k2a, k2b, base + 1u), jax_normal(k2a, k2b, base + 2u) };
    F3 n3 = { jax_normal(k3a, k3b, base + 0u), jax_normal(k3a, k3b, base + 1u), jax_normal(k3a, k3b, base + 2u) };
    F3 n4 = { jax_normal(k4a, k4b, base + 0u), jax_normal(k4a, k4b, base + 1u), jax_normal(k4a, k4b, base + 2u) };

    float ps  = 0.25f * rt;   // POS_SCATTER * r_t
    float vsc = 0.3f  * sig;  // VEL_SCATTER * sigma
    F3 off = { rt * rhat.x, rt * rhat.y, rt * rhat.z };

    F3 xL = { (px.x - off.x) + ps * n1.x, (px.y - off.y) + ps * n1.y, (px.z - off.z) + ps * n1.z };
    F3 xT = { (px.x + off.x) + ps * n2.x, (px.y + off.y) + ps * n2.y, (px.z + off.z) + ps * n2.z };
    F3 vL = { pv.x + vsc * n3.x, pv.y + vsc * n3.y, pv.z + vsc * n3.z };
    F3 vT = { pv.x + vsc * n4.x, pv.y + vsc * n4.y, pv.z + vsc * n4.z };

    F3 uL = vL, uT = vT;
    if (t < T_STEPS - 1) {
        F3 aL = accelF(xL, gm, b2);
        F3 aT = accelF(xT, gm, b2);
        float ts_cur = ts[t];
        float ts_nxt = ts[t + 1];
        float dt = ts_nxt - ts_cur, h = 0.5f * dt;
        ts_cur = ts_nxt;
        // first active step (j = t)
        uL = fma3(h, aL, vL);  uT = fma3(h, aT, vT);   // v1
        xL = fma3(dt, uL, xL); xT = fma3(dt, uT, xT);  // drift
        aL = accelF(xL, gm, b2); aT = accelF(xT, gm, b2);
        uL = fma3(h, aL, uL);  uT = fma3(h, aT, uT);   // v2
        for (int j = t + 1; j < T_STEPS - 1; ++j) {
            ts_nxt = ts[j + 1];
            dt = ts_nxt - ts_cur; ts_cur = ts_nxt;
            h = 0.5f * dt;
            uL = fma3(h, aL, uL);  uT = fma3(h, aT, uT);   // v1_j (reuses prev accel)
            xL = fma3(dt, uL, xL); xT = fma3(dt, uT, xT);  // drift
            aL = accelF(xL, gm, b2); aT = accelF(xT, gm, b2);
            uL = fma3(h, aL, uL);  uT = fma3(h, aT, uT);   // v2_j
        }
    }

    float* ol = w_lead + 6 * t;
    ol[0] = xL.x; ol[1] = xL.y; ol[2] = xL.z;
    ol[3] = uL.x; ol[4] = uL.y; ol[5] = uL.z;
    float* ot = w_trail + 6 * t;
    ot[0] = xT.x; ot[1] = xT.y; ot[2] = xT.z;
    ot[3] = uT.x; ot[4] = uT.y; ot[5] = uT.z;
}

extern "C" void kernel_launch(void* const* d_in, const int* in_sizes, int n_in,
                              void* d_out, int out_size, void* d_ws, size_t ws_size,
                              hipStream_t stream) {
    const float* ts   = (const float*)d_in[0];
    const float* w0   = (const float*)d_in[1];
    const float* pm   = (const float*)d_in[2];
    const float* gm   = (const float*)d_in[3];
    const float* b    = (const float*)d_in[4];
    const int*   seed = (const int*)d_in[5];

    float* out     = (float*)d_out;
    float* w_lead  = out;
    float* w_trail = out + (size_t)T_STEPS * 6;
    float* prog    = out + (size_t)T_STEPS * 12;

    hipLaunchKernelGGL(prog_kernel, dim3(1), dim3(64), 0, stream, ts, w0, gm, b, prog);
    hipLaunchKernelGGL(stream_kernel, dim3(T_STEPS / 64), dim3(64), 0, stream,
                       ts, prog, pm, gm, b, seed, w_lead, w_trail);
}

// Round 2
// 205.739 us; speedup vs baseline: 2.1453x; 2.1453x over previous
//
#include <hip/hip_runtime.h>
#include <stdint.h>

#define T_STEPS 2048
#define LAST (T_STEPS - 1)

struct F3 { float x, y, z; };

__device__ __forceinline__ F3 fma3(float a, F3 b, F3 c) {
    return { fmaf(a, b.x, c.x), fmaf(a, b.y, c.y), fmaf(a, b.z, c.z) };
}

// accel(p) = -gm * p / (|p|^2 + b^2)^1.5
__device__ __forceinline__ F3 accelF(F3 p, float gm, float b2) {
    float r2 = fmaf(p.z, p.z, fmaf(p.y, p.y, fmaf(p.x, p.x, b2)));
    float iv = rsqrtf(r2);
    float c  = -gm * (iv * iv * iv);
    return { c * p.x, c * p.y, c * p.z };
}

__device__ __forceinline__ uint32_t rotl32(uint32_t v, int r) {
    return (v << r) | (v >> (32 - r));
}

// JAX Threefry-2x32, 20 rounds.
__device__ __forceinline__ void tf2x32(uint32_t k0, uint32_t k1, uint32_t c0, uint32_t c1,
                                       uint32_t &o0, uint32_t &o1) {
    uint32_t ks2 = k0 ^ k1 ^ 0x1BD11BDAu;
    uint32_t x0 = c0 + k0, x1 = c1 + k1;
#define TF_R(r) { x0 += x1; x1 = rotl32(x1, r); x1 ^= x0; }
    TF_R(13) TF_R(15) TF_R(26) TF_R(6)   x0 += k1;  x1 += ks2 + 1u;
    TF_R(17) TF_R(29) TF_R(16) TF_R(24)  x0 += ks2; x1 += k0 + 2u;
    TF_R(13) TF_R(15) TF_R(26) TF_R(6)   x0 += k0;  x1 += k1 + 3u;
    TF_R(17) TF_R(29) TF_R(16) TF_R(24)  x0 += k1;  x1 += ks2 + 4u;
    TF_R(13) TF_R(15) TF_R(26) TF_R(6)   x0 += ks2; x1 += k0 + 5u;
#undef TF_R
    o0 = x0; o1 = x1;
}

// XLA ErfInv32 (Giles), w = -log1p(-x*x)
__device__ __forceinline__ float erfinv32(float x) {
    float w = -log1pf(-x * x);
    float p;
    if (w < 5.0f) {
        w -= 2.5f;
        p =              2.81022636e-08f;
        p = fmaf(p, w,   3.43273939e-07f);
        p = fmaf(p, w,  -3.5233877e-06f);
        p = fmaf(p, w,  -4.39150654e-06f);
        p = fmaf(p, w,   0.00021858087f);
        p = fmaf(p, w,  -0.00125372503f);
        p = fmaf(p, w,  -0.00417768164f);
        p = fmaf(p, w,   0.246640727f);
        p = fmaf(p, w,   1.50140941f);
    } else {
        w = sqrtf(w) - 3.0f;
        p =             -0.000200214257f;
        p = fmaf(p, w,   0.000100950558f);
        p = fmaf(p, w,   0.00134934322f);
        p = fmaf(p, w,  -0.00367342844f);
        p = fmaf(p, w,   0.00573950773f);
        p = fmaf(p, w,  -0.0076224613f);
        p = fmaf(p, w,   0.00943887047f);
        p = fmaf(p, w,   1.00167406f);
        p = fmaf(p, w,   2.83297682f);
    }
    return p * x;
}

// jax.random.normal (threefry, partitionable path): bits = x0^x1 of E(key,(0,idx))
__device__ __forceinline__ float jax_normal(uint32_t ka, uint32_t kb, uint32_t idx) {
    uint32_t o0, o1;
    tf2x32(ka, kb, 0u, idx, o0, o1);
    uint32_t bits = o0 ^ o1;
    float f = __uint_as_float((bits >> 9) | 0x3F800000u) - 1.0f;  // [0,1)
    const float LO = -0.99999994f;                                 // nextafter(-1,0)
    float u = fmaxf(LO, fmaf(f, 2.0f, LO));                        // hi-lo rounds to 2.0f
    return 1.41421356f * erfinv32(u);
}

__device__ __forceinline__ int clampT(int i) { return i < LAST ? i : LAST; }

// one progenitor leapfrog step; `a` is the cached accel at current x
#define PROG_STEP(TN) { \
    float dt = (TN) - tcur, h = 0.5f * dt; \
    v = fma3(h, a, v); \
    x = fma3(dt, v, x); \
    a = accelF(x, gm, b2); \
    v = fma3(h, a, v); \
    tcur = (TN); }

// one stream step for both particles (lead/trail, independent ILP chains)
#define STREAM_STEP(TN) { \
    float dt = (TN) - tcur, h = 0.5f * dt; \
    uL = fma3(h, aL, uL); uT = fma3(h, aT, uT); \
    xL = fma3(dt, uL, xL); xT = fma3(dt, uT, xT); \
    aL = accelF(xL, gm, b2); aT = accelF(xT, gm, b2); \
    uL = fma3(h, aL, uL); uT = fma3(h, aT, uT); \
    tcur = (TN); }

__global__ void fused_kernel(const float* __restrict__ ts,
                             const float* __restrict__ w0,
                             const float* __restrict__ mass_p,
                             const float* __restrict__ gm_p,
                             const float* __restrict__ b_p,
                             const int*   __restrict__ seed_p,
                             float* __restrict__ w_lead,
                             float* __restrict__ w_trail,
                             float* __restrict__ prog) {
    const int t = blockIdx.x * blockDim.x + threadIdx.x;
    if (t >= T_STEPS) return;
    const float gm = gm_p[0];
    const float bb = b_p[0];
    const float b2 = bb * bb;
    const float pm = mass_p[0];
    const uint32_t seed = (uint32_t)seed_p[0];

    // ---------- Phase A: integrate progenitor 0 -> t (per-thread, redundant) ----------
    F3 x = { w0[0], w0[1], w0[2] };
    F3 v = { w0[3], w0[4], w0[5] };
    F3 a = accelF(x, gm, b2);
    float tcur = ts[0];

    {
        const int rem = t;                       // number of prog steps for this lane
        float n0 = ts[1], n1 = ts[2], n2 = ts[3], n3 = ts[4];
        int i = 0;
        while (i + 4 <= rem) {
            const int jb = i + 5;                // prefetch next group of 4
            float m0 = ts[clampT(jb)],     m1 = ts[clampT(jb + 1)];
            float m2 = ts[clampT(jb + 2)], m3 = ts[clampT(jb + 3)];
            PROG_STEP(n0) PROG_STEP(n1) PROG_STEP(n2) PROG_STEP(n3)
            n0 = m0; n1 = m1; n2 = m2; n3 = m3;
            i += 4;
        }
        while (i < rem) {
            PROG_STEP(n0)
            n0 = n1; n1 = n2; n2 = n3;
            ++i;
        }
    }
    // now (x, v) = prog state at step t; tcur == ts[t]

    // write prog_ws row t
    {
        float* row = prog + 6 * t;
        row[0] = x.x; row[1] = x.y; row[2] = x.z;
        row[3] = v.x; row[4] = v.y; row[5] = v.z;
    }

    // ---------- initial conditions: scatter + RNG ----------
    uint32_t k1a, k1b, k2a, k2b, k3a, k3b, k4a, k4b;
    tf2x32(0u, seed, 0u, 0u, k1a, k1b);
    tf2x32(0u, seed, 0u, 1u, k2a, k2b);
    tf2x32(0u, seed, 0u, 2u, k3a, k3b);
    tf2x32(0u, seed, 0u, 3u, k4a, k4b);

    float r   = sqrtf(fmaf(x.z, x.z, fmaf(x.y, x.y, x.x * x.x)));
    float cb  = powf(pm / (3.0f * gm), 1.0f / 3.0f);
    float rt  = r * cb;
    float sig = sqrtf(pm / (rt + 1e-8f));
    F3 rhat = { x.x / r, x.y / r, x.z / r };

    uint32_t base = 3u * (uint32_t)t;
    F3 n1v = { jax_normal(k1a, k1b, base + 0u), jax_normal(k1a, k1b, base + 1u), jax_normal(k1a, k1b, base + 2u) };
    F3 n2v = { jax_normal(k2a, k2b, base + 0u), jax_normal(k2a, k2b, base + 1u), jax_normal(k2a, k2b, base + 2u) };
    F3 n3v = { jax_normal(k3a, k3b, base + 0u), jax_normal(k3a, k3b, base + 1u), jax_normal(k3a, k3b, base + 2u) };
    F3 n4v = { jax_normal(k4a, k4b, base + 0u), jax_normal(k4a, k4b, base + 1u), jax_normal(k4a, k4b, base + 2u) };

    float ps  = 0.25f * rt;
    float vsc = 0.3f  * sig;
    F3 off = { rt * rhat.x, rt * rhat.y, rt * rhat.z };

    F3 xL = { (x.x - off.x) + ps * n1v.x, (x.y - off.y) + ps * n1v.y, (x.z - off.z) + ps * n1v.z };
    F3 xT = { (x.x + off.x) + ps * n2v.x, (x.y + off.y) + ps * n2v.y, (x.z + off.z) + ps * n2v.z };
    F3 uL = { v.x + vsc * n3v.x, v.y + vsc * n3v.y, v.z + vsc * n3v.z };
    F3 uT = { v.x + vsc * n4v.x, v.y + vsc * n4v.y, v.z + vsc * n4v.z };

    // ---------- Phase B: stream integration t -> 2046 ----------
    {
        const int rem = LAST - t;                // number of stream steps
        if (rem > 0) {
            F3 aL = accelF(xL, gm, b2);
            F3 aT = accelF(xT, gm, b2);
            float n0 = ts[clampT(t + 1)], n1 = ts[clampT(t + 2)];
            float n2 = ts[clampT(t + 3)], n3 = ts[clampT(t + 4)];
            int i = 0;
            while (i + 4 <= rem) {
                const int jb = t + i + 5;        // prefetch next group of 4
                float m0 = ts[clampT(jb)],     m1 = ts[clampT(jb + 1)];
                float m2 = ts[clampT(jb + 2)], m3 = ts[clampT(jb + 3)];
                STREAM_STEP(n0) STREAM_STEP(n1) STREAM_STEP(n2) STREAM_STEP(n3)
                n0 = m0; n1 = m1; n2 = m2; n3 = m3;
                i += 4;
            }
            while (i < rem) {
                STREAM_STEP(n0)
                n0 = n1; n1 = n2; n2 = n3;
                ++i;
            }
        }
    }

    float* ol = w_lead + 6 * t;
    ol[0] = xL.x; ol[1] = xL.y; ol[2] = xL.z;
    ol[3] = uL.x; ol[4] = uL.y; ol[5] = uL.z;
    float* ot = w_trail + 6 * t;
    ot[0] = xT.x; ot[1] = xT.y; ot[2] = xT.z;
    ot[3] = uT.x; ot[4] = uT.y; ot[5] = uT.z;
}

extern "C" void kernel_launch(void* const* d_in, const int* in_sizes, int n_in,
                              void* d_out, int out_size, void* d_ws, size_t ws_size,
                              hipStream_t stream) {
    const float* ts   = (const float*)d_in[0];
    const float* w0   = (const float*)d_in[1];
    const float* pm   = (const float*)d_in[2];
    const float* gm   = (const float*)d_in[3];
    const float* b    = (const float*)d_in[4];
    const int*   seed = (const int*)d_in[5];

    float* out     = (float*)d_out;
    float* w_lead  = out;
    float* w_trail = out + (size_t)T_STEPS * 6;
    float* prog    = out + (size_t)T_STEPS * 12;

    hipLaunchKernelGGL(fused_kernel, dim3(T_STEPS / 64), dim3(64), 0, stream,
                       ts, w0, pm, gm, b, seed, w_lead, w_trail, prog);
}

// Round 3
// 121.493 us; speedup vs baseline: 3.6330x; 1.6934x over previous
//
#include <hip/hip_runtime.h>
#include <stdint.h>

#define T_STEPS 2048
#define LAST (T_STEPS - 1)

struct F3 { float x, y, z; };

__device__ __forceinline__ F3 fma3(float a, F3 b, F3 c) {
    return { fmaf(a, b.x, c.x), fmaf(a, b.y, c.y), fmaf(a, b.z, c.z) };
}

// accel(p) = -gm * p / (|p|^2 + b^2)^1.5   (bitwise-identical to prior rounds)
__device__ __forceinline__ F3 accelF(F3 p, float gm, float b2) {
    float r2 = fmaf(p.z, p.z, fmaf(p.y, p.y, fmaf(p.x, p.x, b2)));
    float iv = rsqrtf(r2);
    float c  = -gm * (iv * iv * iv);
    return { c * p.x, c * p.y, c * p.z };
}

__device__ __forceinline__ uint32_t rotl32(uint32_t v, int r) {
    return (v << r) | (v >> (32 - r));
}

// JAX Threefry-2x32, 20 rounds.
__device__ __forceinline__ void tf2x32(uint32_t k0, uint32_t k1, uint32_t c0, uint32_t c1,
                                       uint32_t &o0, uint32_t &o1) {
    uint32_t ks2 = k0 ^ k1 ^ 0x1BD11BDAu;
    uint32_t x0 = c0 + k0, x1 = c1 + k1;
#define TF_R(r) { x0 += x1; x1 = rotl32(x1, r); x1 ^= x0; }
    TF_R(13) TF_R(15) TF_R(26) TF_R(6)   x0 += k1;  x1 += ks2 + 1u;
    TF_R(17) TF_R(29) TF_R(16) TF_R(24)  x0 += ks2; x1 += k0 + 2u;
    TF_R(13) TF_R(15) TF_R(26) TF_R(6)   x0 += k0;  x1 += k1 + 3u;
    TF_R(17) TF_R(29) TF_R(16) TF_R(24)  x0 += k1;  x1 += ks2 + 4u;
    TF_R(13) TF_R(15) TF_R(26) TF_R(6)   x0 += ks2; x1 += k0 + 5u;
#undef TF_R
    o0 = x0; o1 = x1;
}

// XLA ErfInv32 (Giles), w = -log1p(-x*x)
__device__ __forceinline__ float erfinv32(float x) {
    float w = -log1pf(-x * x);
    float p;
    if (w < 5.0f) {
        w -= 2.5f;
        p =              2.81022636e-08f;
        p = fmaf(p, w,   3.43273939e-07f);
        p = fmaf(p, w,  -3.5233877e-06f);
        p = fmaf(p, w,  -4.39150654e-06f);
        p = fmaf(p, w,   0.00021858087f);
        p = fmaf(p, w,  -0.00125372503f);
        p = fmaf(p, w,  -0.00417768164f);
        p = fmaf(p, w,   0.246640727f);
        p = fmaf(p, w,   1.50140941f);
    } else {
        w = sqrtf(w) - 3.0f;
        p =             -0.000200214257f;
        p = fmaf(p, w,   0.000100950558f);
        p = fmaf(p, w,   0.00134934322f);
        p = fmaf(p, w,  -0.00367342844f);
        p = fmaf(p, w,   0.00573950773f);
        p = fmaf(p, w,  -0.0076224613f);
        p = fmaf(p, w,   0.00943887047f);
        p = fmaf(p, w,   1.00167406f);
        p = fmaf(p, w,   2.83297682f);
    }
    return p * x;
}

// jax.random.normal (threefry, partitionable path): bits = x0^x1 of E(key,(0,idx))
__device__ __forceinline__ float jax_normal(uint32_t ka, uint32_t kb, uint32_t idx) {
    uint32_t o0, o1;
    tf2x32(ka, kb, 0u, idx, o0, o1);
    uint32_t bits = o0 ^ o1;
    float f = __uint_as_float((bits >> 9) | 0x3F800000u) - 1.0f;  // [0,1)
    const float LO = -0.99999994f;                                 // nextafter(-1,0)
    float u = fmaxf(LO, fmaf(f, 2.0f, LO));                        // hi-lo rounds to 2.0f
    return 1.41421356f * erfinv32(u);
}

// one leapfrog step for a single body; `a` is the cached accel at current x
#define STEP1(TN) { \
    float dt = (TN) - tcur, h = 0.5f * dt; \
    v = fma3(h, a, v); \
    x = fma3(dt, v, x); \
    a = accelF(x, gm, b2); \
    v = fma3(h, a, v); \
    tcur = (TN); }

// run `rem` steps starting with lds index base+1; prefetch 4-deep from padded LDS
#define RUN_CHAIN(base, rem) { \
    float n0 = lts[(base) + 1], n1 = lts[(base) + 2]; \
    float n2 = lts[(base) + 3], n3 = lts[(base) + 4]; \
    int i = 0; \
    while (i + 4 <= (rem)) { \
        const int jb = (base) + i + 5; \
        float m0 = lts[jb], m1 = lts[jb + 1], m2 = lts[jb + 2], m3 = lts[jb + 3]; \
        STEP1(n0) STEP1(n1) STEP1(n2) STEP1(n3) \
        n0 = m0; n1 = m1; n2 = m2; n3 = m3; \
        i += 4; \
    } \
    while (i < (rem)) { \
        STEP1(n0) \
        n0 = n1; n1 = n2; n2 = n3; \
        ++i; \
    } }

// thread layout: gid = 2*t + role; role 0 = lead, role 1 = trail
__global__ void __launch_bounds__(64)
fused_kernel(const float* __restrict__ ts,
             const float* __restrict__ w0,
             const float* __restrict__ mass_p,
             const float* __restrict__ gm_p,
             const float* __restrict__ b_p,
             const int*   __restrict__ seed_p,
             float* __restrict__ w_lead,
             float* __restrict__ w_trail,
             float* __restrict__ prog) {
    __shared__ float lts[T_STEPS + 8];

    // stage ts into LDS (coalesced), pad 8 with last value
    {
        const int l = threadIdx.x;
        for (int k = l; k < T_STEPS; k += 64) lts[k] = ts[k];
        if (l < 8) lts[T_STEPS + l] = ts[LAST];
    }
    __syncthreads();

    const int gid  = blockIdx.x * blockDim.x + threadIdx.x;
    const int t    = gid >> 1;
    const int role = gid & 1;           // 0 = lead, 1 = trail
    if (t >= T_STEPS) return;

    const float gm = gm_p[0];
    const float bb = b_p[0];
    const float b2 = bb * bb;
    const float pm = mass_p[0];
    const uint32_t seed = (uint32_t)seed_p[0];

    // ---------- Phase A: integrate progenitor 0 -> t ----------
    F3 x = { w0[0], w0[1], w0[2] };
    F3 v = { w0[3], w0[4], w0[5] };
    F3 a = accelF(x, gm, b2);
    float tcur = lts[0];

    RUN_CHAIN(0, t)
    // (x, v) = prog state at step t; tcur == ts[t]

    if (role == 0) {
        float* row = prog + 6 * t;
        row[0] = x.x; row[1] = x.y; row[2] = x.z;
        row[3] = v.x; row[4] = v.y; row[5] = v.z;
    }

    // ---------- initial conditions: scatter + RNG ----------
    // split(key(seed),4): pos key idx = role (0->k1, 1->k2); vel key idx = 2+role (k3/k4)
    uint32_t kpa, kpb, kva, kvb;
    tf2x32(0u, seed, 0u, (uint32_t)role,      kpa, kpb);
    tf2x32(0u, seed, 0u, (uint32_t)(2 + role), kva, kvb);

    float r   = sqrtf(fmaf(x.z, x.z, fmaf(x.y, x.y, x.x * x.x)));
    float cb  = powf(pm / (3.0f * gm), 1.0f / 3.0f);
    float rt  = r * cb;
    float sig = sqrtf(pm / (rt + 1e-8f));
    F3 rhat = { x.x / r, x.y / r, x.z / r };

    uint32_t base = 3u * (uint32_t)t;
    F3 np = { jax_normal(kpa, kpb, base + 0u), jax_normal(kpa, kpb, base + 1u), jax_normal(kpa, kpb, base + 2u) };
    F3 nv = { jax_normal(kva, kvb, base + 0u), jax_normal(kva, kvb, base + 1u), jax_normal(kva, kvb, base + 2u) };

    float ps  = 0.25f * rt;
    float vsc = 0.3f  * sig;
    float sgn = role ? 1.0f : -1.0f;
    F3 off = { sgn * (rt * rhat.x), sgn * (rt * rhat.y), sgn * (rt * rhat.z) };

    // reuse (x, v, a, tcur) as the particle state for phase B
    x = F3{ (x.x + off.x) + ps * np.x, (x.y + off.y) + ps * np.y, (x.z + off.z) + ps * np.z };
    v = F3{ v.x + vsc * nv.x, v.y + vsc * nv.y, v.z + vsc * nv.z };

    // ---------- Phase B: stream integration t -> 2046 ----------
    const int rem = LAST - t;
    if (rem > 0) {
        a = accelF(x, gm, b2);
        RUN_CHAIN(t, rem)
    }

    float* o = (role ? w_trail : w_lead) + 6 * t;
    o[0] = x.x; o[1] = x.y; o[2] = x.z;
    o[3] = v.x; o[4] = v.y; o[5] = v.z;
}

extern "C" void kernel_launch(void* const* d_in, const int* in_sizes, int n_in,
                              void* d_out, int out_size, void* d_ws, size_t ws_size,
                              hipStream_t stream) {
    const float* ts   = (const float*)d_in[0];
    const float* w0   = (const float*)d_in[1];
    const float* pm   = (const float*)d_in[2];
    const float* gm   = (const float*)d_in[3];
    const float* b    = (const float*)d_in[4];
    const int*   seed = (const int*)d_in[5];

    float* out     = (float*)d_out;
    float* w_lead  = out;
    float* w_trail = out + (size_t)T_STEPS * 6;
    float* prog    = out + (size_t)T_STEPS * 12;

    hipLaunchKernelGGL(fused_kernel, dim3(2 * T_STEPS / 64), dim3(64), 0, stream,
                       ts, w0, pm, gm, b, seed, w_lead, w_trail, prog);
}

// Round 4
// 108.462 us; speedup vs baseline: 4.0694x; 1.1201x over previous
//
#include <hip/hip_runtime.h>
#include <stdint.h>

#define T_STEPS 2048
#define LAST (T_STEPS - 1)
#define NSTEP (T_STEPS - 1)      // 2047 leapfrog steps total (dts entries)

struct F3 { float x, y, z; };

__device__ __forceinline__ F3 fma3(float a, F3 b, F3 c) {
    return { fmaf(a, b.x, c.x), fmaf(a, b.y, c.y), fmaf(a, b.z, c.z) };
}

// accel(p) = -gm * p / (|p|^2 + b^2)^1.5
// gm == 1.0 in this problem, so (gmneg*iv)*(iv*iv) == -(iv*iv*iv) bitwise —
// identical product order to the previous -gm*((iv*iv)*iv).
// rsqrt forced to a single v_rsq_f32 (keep it off OCML's guarded path).
__device__ __forceinline__ F3 accelF(F3 p, float gmneg, float b2) {
    float r2 = fmaf(p.z, p.z, fmaf(p.y, p.y, fmaf(p.x, p.x, b2)));
    float iv;
    asm("v_rsq_f32 %0, %1" : "=v"(iv) : "v"(r2));
    float iv2 = iv * iv;
    float giv = gmneg * iv;      // parallel with iv2
    float c   = iv2 * giv;
    return { c * p.x, c * p.y, c * p.z };
}

__device__ __forceinline__ uint32_t rotl32(uint32_t v, int r) {
    return (v << r) | (v >> (32 - r));
}

// JAX Threefry-2x32, 20 rounds.
__device__ __forceinline__ void tf2x32(uint32_t k0, uint32_t k1, uint32_t c0, uint32_t c1,
                                       uint32_t &o0, uint32_t &o1) {
    uint32_t ks2 = k0 ^ k1 ^ 0x1BD11BDAu;
    uint32_t x0 = c0 + k0, x1 = c1 + k1;
#define TF_R(r) { x0 += x1; x1 = rotl32(x1, r); x1 ^= x0; }
    TF_R(13) TF_R(15) TF_R(26) TF_R(6)   x0 += k1;  x1 += ks2 + 1u;
    TF_R(17) TF_R(29) TF_R(16) TF_R(24)  x0 += ks2; x1 += k0 + 2u;
    TF_R(13) TF_R(15) TF_R(26) TF_R(6)   x0 += k0;  x1 += k1 + 3u;
    TF_R(17) TF_R(29) TF_R(16) TF_R(24)  x0 += k1;  x1 += ks2 + 4u;
    TF_R(13) TF_R(15) TF_R(26) TF_R(6)   x0 += ks2; x1 += k0 + 5u;
#undef TF_R
    o0 = x0; o1 = x1;
}

// XLA ErfInv32 (Giles), w = -log1p(-x*x)
__device__ __forceinline__ float erfinv32(float x) {
    float w = -log1pf(-x * x);
    float p;
    if (w < 5.0f) {
        w -= 2.5f;
        p =              2.81022636e-08f;
        p = fmaf(p, w,   3.43273939e-07f);
        p = fmaf(p, w,  -3.5233877e-06f);
        p = fmaf(p, w,  -4.39150654e-06f);
        p = fmaf(p, w,   0.00021858087f);
        p = fmaf(p, w,  -0.00125372503f);
        p = fmaf(p, w,  -0.00417768164f);
        p = fmaf(p, w,   0.246640727f);
        p = fmaf(p, w,   1.50140941f);
    } else {
        w = sqrtf(w) - 3.0f;
        p =             -0.000200214257f;
        p = fmaf(p, w,   0.000100950558f);
        p = fmaf(p, w,   0.00134934322f);
        p = fmaf(p, w,  -0.00367342844f);
        p = fmaf(p, w,   0.00573950773f);
        p = fmaf(p, w,  -0.0076224613f);
        p = fmaf(p, w,   0.00943887047f);
        p = fmaf(p, w,   1.00167406f);
        p = fmaf(p, w,   2.83297682f);
    }
    return p * x;
}

// jax.random.normal (threefry, partitionable path): bits = x0^x1 of E(key,(0,idx))
__device__ __forceinline__ float jax_normal(uint32_t ka, uint32_t kb, uint32_t idx) {
    uint32_t o0, o1;
    tf2x32(ka, kb, 0u, idx, o0, o1);
    uint32_t bits = o0 ^ o1;
    float f = __uint_as_float((bits >> 9) | 0x3F800000u) - 1.0f;  // [0,1)
    const float LO = -0.99999994f;                                 // nextafter(-1,0)
    float u = fmaxf(LO, fmaf(f, 2.0f, LO));                        // hi-lo rounds to 2.0f
    return 1.41421356f * erfinv32(u);
}

// one leapfrog step; `a` is cached accel at current x; nk = (dt, h)
#define STEP1(NK) { \
    v = fma3((NK).y, a, v); \
    x = fma3((NK).x, v, x); \
    a = accelF(x, gmneg, b2); \
    v = fma3((NK).y, a, v); }

// consume dth[base .. base+rem-1], 4-deep register prefetch
#define RUN_CHAIN(base, rem) { \
    float2 n0 = dth[(base) + 0], n1 = dth[(base) + 1]; \
    float2 n2 = dth[(base) + 2], n3 = dth[(base) + 3]; \
    int i = 0; \
    while (i + 4 <= (rem)) { \
        const int jb = (base) + i + 4; \
        float2 m0 = dth[jb],     m1 = dth[jb + 1]; \
        float2 m2 = dth[jb + 2], m3 = dth[jb + 3]; \
        STEP1(n0) STEP1(n1) STEP1(n2) STEP1(n3) \
        n0 = m0; n1 = m1; n2 = m2; n3 = m3; \
        i += 4; \
    } \
    if (i < (rem)) { STEP1(n0) ++i; } \
    if (i < (rem)) { STEP1(n1) ++i; } \
    if (i < (rem)) { STEP1(n2) ++i; } }

// thread layout: gid = 2*t + role; role 0 = lead, 1 = trail
__global__ void __launch_bounds__(64)
fused_kernel(const float* __restrict__ ts,
             const float* __restrict__ w0,
             const float* __restrict__ mass_p,
             const float* __restrict__ gm_p,
             const float* __restrict__ b_p,
             const int*   __restrict__ seed_p,
             float* __restrict__ w_lead,
             float* __restrict__ w_trail,
             float* __restrict__ prog) {
    __shared__ float2 dth[NSTEP + 8];   // (dt_j, 0.5*dt_j), j = 0..2046, zero pad

    {
        const int l = threadIdx.x;
        for (int j = l; j < NSTEP + 8; j += 64) {
            float dt = (j < NSTEP) ? (ts[j + 1] - ts[j]) : 0.0f;
            dth[j] = make_float2(dt, 0.5f * dt);
        }
    }
    __syncthreads();

    const int gid  = blockIdx.x * blockDim.x + threadIdx.x;
    const int t    = gid >> 1;
    const int role = gid & 1;           // 0 = lead, 1 = trail
    if (t >= T_STEPS) return;

    const float gm = gm_p[0];
    const float gmneg = -gm;
    const float bb = b_p[0];
    const float b2 = bb * bb;
    const float pm = mass_p[0];
    const uint32_t seed = (uint32_t)seed_p[0];

    // ---------- Phase A: integrate progenitor 0 -> t ----------
    F3 x = { w0[0], w0[1], w0[2] };
    F3 v = { w0[3], w0[4], w0[5] };
    F3 a = accelF(x, gmneg, b2);

    RUN_CHAIN(0, t)
    // (x, v) = prog state at step t

    if (role == 0) {
        float* row = prog + 6 * t;
        row[0] = x.x; row[1] = x.y; row[2] = x.z;
        row[3] = v.x; row[4] = v.y; row[5] = v.z;
    }

    // ---------- initial conditions: scatter + RNG ----------
    uint32_t kpa, kpb, kva, kvb;
    tf2x32(0u, seed, 0u, (uint32_t)role,       kpa, kpb);
    tf2x32(0u, seed, 0u, (uint32_t)(2 + role), kva, kvb);

    float r   = sqrtf(fmaf(x.z, x.z, fmaf(x.y, x.y, x.x * x.x)));
    float cb  = powf(pm / (3.0f * gm), 1.0f / 3.0f);
    float rt  = r * cb;
    float sig = sqrtf(pm / (rt + 1e-8f));
    F3 rhat = { x.x / r, x.y / r, x.z / r };

    uint32_t base = 3u * (uint32_t)t;
    F3 np = { jax_normal(kpa, kpb, base + 0u), jax_normal(kpa, kpb, base + 1u), jax_normal(kpa, kpb, base + 2u) };
    F3 nv = { jax_normal(kva, kvb, base + 0u), jax_normal(kva, kvb, base + 1u), jax_normal(kva, kvb, base + 2u) };

    float ps  = 0.25f * rt;
    float vsc = 0.3f  * sig;
    float sgn = role ? 1.0f : -1.0f;
    F3 off = { sgn * (rt * rhat.x), sgn * (rt * rhat.y), sgn * (rt * rhat.z) };

    x = F3{ (x.x + off.x) + ps * np.x, (x.y + off.y) + ps * np.y, (x.z + off.z) + ps * np.z };
    v = F3{ v.x + vsc * nv.x, v.y + vsc * nv.y, v.z + vsc * nv.z };

    // ---------- Phase B: stream integration, steps t .. 2046 ----------
    const int rem = LAST - t;
    if (rem > 0) {
        a = accelF(x, gmneg, b2);
        RUN_CHAIN(t, rem)
    }

    float* o = (role ? w_trail : w_lead) + 6 * t;
    o[0] = x.x; o[1] = x.y; o[2] = x.z;
    o[3] = v.x; o[4] = v.y; o[5] = v.z;
}

extern "C" void kernel_launch(void* const* d_in, const int* in_sizes, int n_in,
                              void* d_out, int out_size, void* d_ws, size_t ws_size,
                              hipStream_t stream) {
    const float* ts   = (const float*)d_in[0];
    const float* w0   = (const float*)d_in[1];
    const float* pm   = (const float*)d_in[2];
    const float* gm   = (const float*)d_in[3];
    const float* b    = (const float*)d_in[4];
    const int*   seed = (const int*)d_in[5];

    float* out     = (float*)d_out;
    float* w_lead  = out;
    float* w_trail = out + (size_t)T_STEPS * 6;
    float* prog    = out + (size_t)T_STEPS * 12;

    hipLaunchKernelGGL(fused_kernel, dim3(2 * T_STEPS / 64), dim3(64), 0, stream,
                       ts, w0, pm, gm, b, seed, w_lead, w_trail, prog);
}

// Round 5
// 79.889 us; speedup vs baseline: 5.5249x; 1.3577x over previous
//
#include <hip/hip_runtime.h>
#include <stdint.h>

#define T_STEPS 2048
#define LAST (T_STEPS - 1)
#define NSTEP (T_STEPS - 1)      // 2047 leapfrog steps total

struct F3 { float x, y, z; };

__device__ __forceinline__ F3 fma3(float a, F3 b, F3 c) {
    return { fmaf(a, b.x, c.x), fmaf(a, b.y, c.y), fmaf(a, b.z, c.z) };
}

// accel(p) = -gm * p / (|p|^2 + b^2)^1.5   (bitwise-identical to R3)
__device__ __forceinline__ F3 accelF(F3 p, float gmneg, float b2) {
    float r2 = fmaf(p.z, p.z, fmaf(p.y, p.y, fmaf(p.x, p.x, b2)));
    float iv;
    asm("v_rsq_f32 %0, %1" : "=v"(iv) : "v"(r2));
    float iv2 = iv * iv;
    float giv = gmneg * iv;
    float c   = iv2 * giv;
    return { c * p.x, c * p.y, c * p.z };
}

__device__ __forceinline__ uint32_t rotl32(uint32_t v, int r) {
    return (v << r) | (v >> (32 - r));
}

// JAX Threefry-2x32, 20 rounds.
__device__ __forceinline__ void tf2x32(uint32_t k0, uint32_t k1, uint32_t c0, uint32_t c1,
                                       uint32_t &o0, uint32_t &o1) {
    uint32_t ks2 = k0 ^ k1 ^ 0x1BD11BDAu;
    uint32_t x0 = c0 + k0, x1 = c1 + k1;
#define TF_R(r) { x0 += x1; x1 = rotl32(x1, r); x1 ^= x0; }
    TF_R(13) TF_R(15) TF_R(26) TF_R(6)   x0 += k1;  x1 += ks2 + 1u;
    TF_R(17) TF_R(29) TF_R(16) TF_R(24)  x0 += ks2; x1 += k0 + 2u;
    TF_R(13) TF_R(15) TF_R(26) TF_R(6)   x0 += k0;  x1 += k1 + 3u;
    TF_R(17) TF_R(29) TF_R(16) TF_R(24)  x0 += k1;  x1 += ks2 + 4u;
    TF_R(13) TF_R(15) TF_R(26) TF_R(6)   x0 += ks2; x1 += k0 + 5u;
#undef TF_R
    o0 = x0; o1 = x1;
}

// XLA ErfInv32 (Giles), w = -log1p(-x*x)
__device__ __forceinline__ float erfinv32(float x) {
    float w = -log1pf(-x * x);
    float p;
    if (w < 5.0f) {
        w -= 2.5f;
        p =              2.81022636e-08f;
        p = fmaf(p, w,   3.43273939e-07f);
        p = fmaf(p, w,  -3.5233877e-06f);
        p = fmaf(p, w,  -4.39150654e-06f);
        p = fmaf(p, w,   0.00021858087f);
        p = fmaf(p, w,  -0.00125372503f);
        p = fmaf(p, w,  -0.00417768164f);
        p = fmaf(p, w,   0.246640727f);
        p = fmaf(p, w,   1.50140941f);
    } else {
        w = sqrtf(w) - 3.0f;
        p =             -0.000200214257f;
        p = fmaf(p, w,   0.000100950558f);
        p = fmaf(p, w,   0.00134934322f);
        p = fmaf(p, w,  -0.00367342844f);
        p = fmaf(p, w,   0.00573950773f);
        p = fmaf(p, w,  -0.0076224613f);
        p = fmaf(p, w,   0.00943887047f);
        p = fmaf(p, w,   1.00167406f);
        p = fmaf(p, w,   2.83297682f);
    }
    return p * x;
}

// jax.random.normal (threefry, partitionable path): bits = x0^x1 of E(key,(0,idx))
__device__ __forceinline__ float jax_normal(uint32_t ka, uint32_t kb, uint32_t idx) {
    uint32_t o0, o1;
    tf2x32(ka, kb, 0u, idx, o0, o1);
    uint32_t bits = o0 ^ o1;
    float f = __uint_as_float((bits >> 9) | 0x3F800000u) - 1.0f;  // [0,1)
    const float LO = -0.99999994f;                                 // nextafter(-1,0)
    float u = fmaxf(LO, fmaf(f, 2.0f, LO));                        // hi-lo rounds to 2.0f
    return 1.41421356f * erfinv32(u);
}

// merged mid-step: drift with dt (NK.x), accel, merged kick with hh (NK.y)
#define STEP_M(NK) { \
    x = fma3((NK).x, v, x); \
    a = accelF(x, gmneg, b2); \
    v = fma3((NK).y, a, v); }

// integrate steps [base, base+rem) with half-kick entry/exit (exact reference
// boundaries); interior kicks merged: hh_j = 0.5*dt_j + 0.5*dt_{j+1}
#define RUN_PHASE(base, rem) \
    if ((rem) > 0) { \
        a = accelF(x, gmneg, b2); \
        float2 first = dth[(base)]; \
        v = fma3(0.5f * first.x, a, v);                /* v1_s (exact half kick) */ \
        const int nm = (rem) - 1;                      /* merged steps */ \
        float2 n0 = dth[(base) + 0], n1 = dth[(base) + 1]; \
        float2 n2 = dth[(base) + 2], n3 = dth[(base) + 3]; \
        float2 n4 = dth[(base) + 4], n5 = dth[(base) + 5]; \
        float2 n6 = dth[(base) + 6], n7 = dth[(base) + 7]; \
        int i = 0; \
        while (i + 8 <= nm) { \
            const int jb = (base) + i + 8; \
            float2 m0 = dth[jb + 0], m1 = dth[jb + 1], m2 = dth[jb + 2], m3 = dth[jb + 3]; \
            float2 m4 = dth[jb + 4], m5 = dth[jb + 5], m6 = dth[jb + 6], m7 = dth[jb + 7]; \
            STEP_M(n0) STEP_M(n1) STEP_M(n2) STEP_M(n3) \
            STEP_M(n4) STEP_M(n5) STEP_M(n6) STEP_M(n7) \
            n0 = m0; n1 = m1; n2 = m2; n3 = m3; \
            n4 = m4; n5 = m5; n6 = m6; n7 = m7; \
            i += 8; \
        } \
        while (i < nm) { \
            float2 nk = dth[(base) + i]; \
            STEP_M(nk) \
            ++i; \
        } \
        float2 lastk = dth[(base) + nm]; \
        x = fma3(lastk.x, v, x);                       /* final drift */ \
        a = accelF(x, gmneg, b2); \
        v = fma3(0.5f * lastk.x, a, v);                /* exact final half kick */ \
    }

// thread layout: gid = 2*t + role; role 0 = lead, 1 = trail
__global__ void __launch_bounds__(64)
fused_kernel(const float* __restrict__ ts,
             const float* __restrict__ w0,
             const float* __restrict__ mass_p,
             const float* __restrict__ gm_p,
             const float* __restrict__ b_p,
             const int*   __restrict__ seed_p,
             float* __restrict__ w_lead,
             float* __restrict__ w_trail,
             float* __restrict__ prog) {
    __shared__ float2 dth[NSTEP + 16];   // (dt_j, hh_j); zero pad for prefetch overrun

    {
        const int l = threadIdx.x;
        for (int j = l; j < NSTEP + 16; j += 64) {
            float dt = 0.0f, hh = 0.0f;
            if (j < NSTEP) {
                float t0 = ts[j], t1 = ts[j + 1];
                dt = t1 - t0;
                float dtn = (j + 1 < NSTEP) ? (ts[j + 2] - t1) : 0.0f;
                hh = fmaf(0.5f, dtn, 0.5f * dt);   // h_j + h_{j+1}
            }
            dth[j] = make_float2(dt, hh);
        }
    }
    __syncthreads();

    const int gid  = blockIdx.x * blockDim.x + threadIdx.x;
    const int t    = gid >> 1;
    const int role = gid & 1;           // 0 = lead, 1 = trail
    if (t >= T_STEPS) return;

    const float gm = gm_p[0];
    const float gmneg = -gm;
    const float bb = b_p[0];
    const float b2 = bb * bb;
    const float pm = mass_p[0];
    const uint32_t seed = (uint32_t)seed_p[0];

    // ---------- Phase A: progenitor, steps [0, t) ----------
    F3 x = { w0[0], w0[1], w0[2] };
    F3 v = { w0[3], w0[4], w0[5] };
    F3 a;

    RUN_PHASE(0, t)
    // (x, v) = prog full state at index t

    if (role == 0) {
        float* row = prog + 6 * t;
        row[0] = x.x; row[1] = x.y; row[2] = x.z;
        row[3] = v.x; row[4] = v.y; row[5] = v.z;
    }

    // ---------- initial conditions: scatter + RNG ----------
    uint32_t kpa, kpb, kva, kvb;
    tf2x32(0u, seed, 0u, (uint32_t)role,       kpa, kpb);
    tf2x32(0u, seed, 0u, (uint32_t)(2 + role), kva, kvb);

    float r   = sqrtf(fmaf(x.z, x.z, fmaf(x.y, x.y, x.x * x.x)));
    float cb  = powf(pm / (3.0f * gm), 1.0f / 3.0f);
    float rt  = r * cb;
    float sig = sqrtf(pm / (rt + 1e-8f));
    F3 rhat = { x.x / r, x.y / r, x.z / r };

    uint32_t base3 = 3u * (uint32_t)t;
    F3 np = { jax_normal(kpa, kpb, base3 + 0u), jax_normal(kpa, kpb, base3 + 1u), jax_normal(kpa, kpb, base3 + 2u) };
    F3 nv = { jax_normal(kva, kvb, base3 + 0u), jax_normal(kva, kvb, base3 + 1u), jax_normal(kva, kvb, base3 + 2u) };

    float ps  = 0.25f * rt;
    float vsc = 0.3f  * sig;
    float sgn = role ? 1.0f : -1.0f;
    F3 off = { sgn * (rt * rhat.x), sgn * (rt * rhat.y), sgn * (rt * rhat.z) };

    x = F3{ (x.x + off.x) + ps * np.x, (x.y + off.y) + ps * np.y, (x.z + off.z) + ps * np.z };
    v = F3{ v.x + vsc * nv.x, v.y + vsc * nv.y, v.z + vsc * nv.z };

    // ---------- Phase B: stream, steps [t, 2047) ----------
    RUN_PHASE(t, LAST - t)

    float* o = (role ? w_trail : w_lead) + 6 * t;
    o[0] = x.x; o[1] = x.y; o[2] = x.z;
    o[3] = v.x; o[4] = v.y; o[5] = v.z;
}

extern "C" void kernel_launch(void* const* d_in, const int* in_sizes, int n_in,
                              void* d_out, int out_size, void* d_ws, size_t ws_size,
                              hipStream_t stream) {
    const float* ts   = (const float*)d_in[0];
    const float* w0   = (const float*)d_in[1];
    const float* pm   = (const float*)d_in[2];
    const float* gm   = (const float*)d_in[3];
    const float* b    = (const float*)d_in[4];
    const int*   seed = (const int*)d_in[5];

    float* out     = (float*)d_out;
    float* w_lead  = out;
    float* w_trail = out + (size_t)T_STEPS * 6;
    float* prog    = out + (size_t)T_STEPS * 12;

    hipLaunchKernelGGL(fused_kernel, dim3(2 * T_STEPS / 64), dim3(64), 0, stream,
                       ts, w0, pm, gm, b, seed, w_lead, w_trail, prog);
}